// Round 1
// baseline (94.001 us; speedup 1.0000x reference)
//
#include <hip/hip_runtime.h>
#include <stdint.h>

// out[b,j,:] = sym[b,j,:] + sum_{i!=j} (sym[b,i,:] @ W[rel(i,j)].T + bias[rel(i,j)])
// B=8, N=1024, D=128, 6 relations.
//
// Linearity rewrite:  agg[j] = sum_r (sum_{i!=j, rel=r} sym[i]) @ W[r].T + cnt_r(j)*bias[r]
//  1. prep: symT bf16 [8][128 e][1024 i]; WtB bf16 blocked; T4[b][quarter][e] colsums
//  2. fused (512 thr = 8 e-waves): classify -> masked MFMA (S_r = M_r @ symT, r<5)
//     -> S5 = T - sym[j] - sum S_r -> S @ Wt (K=768) -> + sym + cnt*bias.
//
// R11 (this round): R10 was stall-bound (44us vs ~15us modeled issue; VALU 41%,
// Mfma 11%, HBM 2%). Root cause: per-chunk __syncthreads implicitly drains the
// just-issued next-chunk DMA (vmcnt(0) per chunk = T4 violation) + 12 barriers
// couple all waves + VGPR=52 starves the scheduler. Fixes:
//  (1) self-sufficient wave staging: wave w DMAs exactly the 16 e-rows it reads
//      (same LDS seg<->content map as R10, read path unchanged) -> phase 2 is
//      BARRIER-FREE with counted s_waitcnt vmcnt(4); all other barriers are raw
//      s_barrier + lgkmcnt(0) only (vmem never drained by sync).
//  (2) __launch_bounds__(512,4): VGPR cap 128 (LDS pins 2 blocks/CU anyway).
//  (3) 6 -> 5 relations: S5 by complement from precomputed T (prep blocks
//      352..383). -17% phase-2 MFMA, -14% mask VALU, cnt5 = 1023 - sum.

typedef __attribute__((ext_vector_type(8))) short bf16x8;
typedef __attribute__((ext_vector_type(4))) float f32x4;
union U4B { uint4 u; bf16x8 b; };

#if defined(__has_builtin)
#  if __has_builtin(__builtin_amdgcn_global_load_lds)
#    define HAVE_GLL 1
#  endif
#  if __has_builtin(__builtin_amdgcn_mul_u24)
#    define OH_MUL24 1
#  endif
#endif

__device__ __forceinline__ uint16_t f2bf(float f) {
    union { float f; uint32_t u; } v; v.f = f;
    uint32_t u = v.u;
    uint32_t r = (u + 0x7FFFu + ((u >> 16) & 1u)) >> 16;  // RNE
    return (uint16_t)r;
}

// raw barrier: orders LDS only; never drains vmcnt (DMA stays in flight).
#define BARRIER_LGKM() do {                                   \
    asm volatile("s_waitcnt lgkmcnt(0)" ::: "memory");        \
    __builtin_amdgcn_s_barrier();                             \
    asm volatile("" ::: "memory");                            \
} while (0)

// ---------------------------------------------------------------------------
// prep: blocks 0..255: transpose X[b][i][e] fp32 -> symT[b][e][i] bf16 (64x64)
//       blocks 256..351: W[r][ep][e] fp32 -> WtB blocked bf16
//       blocks 352..383: T4[b][qq][e] = sum_{i in qq*256..+256} X[b][i][e]
// ---------------------------------------------------------------------------
__global__ __launch_bounds__(256)
void prep_kernel(const float* __restrict__ X, const float* __restrict__ W,
                 uint16_t* __restrict__ symT, uint16_t* __restrict__ WtB,
                 float* __restrict__ T4) {
    const int blk = blockIdx.x, tid = threadIdx.x;
    if (blk < 256) {
        __shared__ float T[64 * 65];
        const int b = blk & 7, z = blk >> 3, it = z & 15, et = z >> 4;
        const int i0 = it * 64, e0 = et * 64;
        const float4* Xf = (const float4*)X;
#pragma unroll
        for (int s = 0; s < 4; ++s) {
            int il = s * 16 + (tid >> 4), e4 = tid & 15;
            float4 v = Xf[((size_t)b << 15) + (size_t)((i0 + il) << 5) + (e0 >> 2) + e4];
            T[il * 65 + e4 * 4 + 0] = v.x;
            T[il * 65 + e4 * 4 + 1] = v.y;
            T[il * 65 + e4 * 4 + 2] = v.z;
            T[il * 65 + e4 * 4 + 3] = v.w;
        }
        __syncthreads();
#pragma unroll
        for (int s = 0; s < 4; ++s) {
            int el = s * 16 + (tid >> 4), il4 = tid & 15;
            uint16_t h0 = f2bf(T[(il4 * 4 + 0) * 65 + el]);
            uint16_t h1 = f2bf(T[(il4 * 4 + 1) * 65 + el]);
            uint16_t h2 = f2bf(T[(il4 * 4 + 2) * 65 + el]);
            uint16_t h3 = f2bf(T[(il4 * 4 + 3) * 65 + el]);
            uint2 pk = { (uint32_t)h0 | ((uint32_t)h1 << 16),
                         (uint32_t)h2 | ((uint32_t)h3 << 16) };
            *(uint2*)&symT[((size_t)b << 17) + ((size_t)(e0 + el) << 10) + i0 + il4 * 4] = pk;
        }
    } else if (blk < 352) {
        int g = (blk - 256) * 256 + tid;          // 0..24575 float4s of W
        float4 v = ((const float4*)W)[g];
        int r = g >> 12, rem = g & 4095, ep = rem >> 5, e4 = rem & 31;
        int kb = r * 4 + (e4 >> 3);               // k = r*128 + e4*4+t
        int kc = (e4 & 7) * 4;
        uint16_t h0 = f2bf(v.x), h1 = f2bf(v.y), h2 = f2bf(v.z), h3 = f2bf(v.w);
        uint2 pk = { (uint32_t)h0 | ((uint32_t)h1 << 16),
                     (uint32_t)h2 | ((uint32_t)h3 << 16) };
        *(uint2*)&WtB[((size_t)(kb * 128 + ep)) * 32 + kc] = pk;
    } else {
        // T4: per-b quarter column sums (fp32), 32 blocks = (b, quarter)
        const int z = blk - 352, bb = z >> 2, qq = z & 3;
        const int e = tid & 127, half = tid >> 7;
        const float* base = X + (((size_t)(bb << 10) + (qq << 8) + (half << 7)) << 7) + e;
        float s = 0.f;
#pragma unroll 8
        for (int itr = 0; itr < 128; ++itr) s += base[(size_t)itr << 7];
        __shared__ float red[256];
        red[tid] = s;
        __syncthreads();
        if (tid < 128) T4[(z << 7) + tid] = red[tid] + red[tid + 128];
    }
}

// ---------------------------------------------------------------------------
// fused kernel: grid 512 = 8b x 64jt (16 j per block), 512 thr = 8 waves.
// LDS map (81920 B -> 2 blocks/CU):
//   @0     symTS[2] double buffer, 32768 B each; wave w owns bytes
//          [w*4096, (w+1)*4096) of each buffer (16 e-rows x 256 B, 16B segs
//          XOR-swizzled seg' = seg ^ (e&15)); buf1 head doubles as posS (8 KB)
//          during classify; after phase 2 the region holds SA (24832 B @0) +
//          partial (33792 B @24832)
//   @65536 rel32: 16 j x 256 dwords, dword-pair swizzle (u ^ 2m), 16384 B
// ---------------------------------------------------------------------------
#define SP 776

__global__ __launch_bounds__(512, 4)
void fused_kernel(const float* __restrict__ sym, const float* __restrict__ pos,
                  const uint16_t* __restrict__ symT, const uint16_t* __restrict__ WtB,
                  const float* __restrict__ bias, const float* __restrict__ T4,
                  float* __restrict__ out) {
    __shared__ __align__(16) char smem[81920];
    uint16_t* symTS   = (uint16_t*)smem;
    float2*   posS    = (float2*)(smem + 32768);
    uint16_t* SA      = (uint16_t*)smem;
    float*    partial = (float*)(smem + 24832);
    uint32_t* rel32   = (uint32_t*)(smem + 65536);

    const int blk = blockIdx.x;
    const int b = blk & 7, jt = blk >> 3, j0 = jt * 16;
    const int tid = threadIdx.x;
    const int w = tid >> 6, lane = tid & 63, m = lane & 15, q = lane >> 4;

    const uint16_t* symTb = symT + ((size_t)b << 17);

    // self-sufficient staging: wave w stages exactly its own 16 e-rows.
    // issue s, lane l -> e = w*16 + s*4 + (l>>4), LDS seg (l&15) gets global
    // seg (l&15)^(e&15)  [identical seg<->content map to the read side].
    int goff[4];
#pragma unroll
    for (int s = 0; s < 4; ++s) {
        int e = (w << 4) + (s << 2) + (lane >> 4);
        int sg = (lane & 15) ^ (e & 15);
        goff[s] = (e << 10) + (sg << 3);        // halfword units; + cidx*128
    }
    const int lwb = w << 12;                    // wave's byte base in a buffer

    auto issue_chunk = [&](int cidx, int bufsel) {
#ifdef HAVE_GLL
#pragma unroll
        for (int s = 0; s < 4; ++s) {
            const uint16_t* gp = symTb + goff[s] + cidx * 128;
            char* lp = smem + bufsel * 32768 + lwb + s * 1024;   // wave-uniform
            typedef const __attribute__((address_space(1))) uint32_t gu32;
            typedef __attribute__((address_space(3))) uint32_t lu32;
            __builtin_amdgcn_global_load_lds((gu32*)gp, (lu32*)lp, 16, 0, 0);
        }
#else
#pragma unroll
        for (int s = 0; s < 4; ++s) {
            uint4 v = *(const uint4*)(symTb + goff[s] + cidx * 128);
            *(uint4*)(smem + bufsel * 32768 + lwb + s * 1024 + lane * 16) = v;
        }
#endif
    };

    // ---- phase 0: stage positions (buf1 head; dead before buf1's first DMA)
    const float2* pos2 = (const float2*)pos + ((size_t)b << 10);
    float2 p0 = pos2[tid], p1 = pos2[tid + 512];
    issue_chunk(0, 0);                     // chunk-0 DMA flies under classify
    posS[tid] = p0;
    posS[tid + 512] = p1;
    BARRIER_LGKM();

    // ---- phase 1: classify 16 j x 1024 i -> one-hot bytes (0 on diagonal) ----
    {
        const int mm = tid & 15, grp = tid >> 4;    // grp 0..31: 32 i's each
        const int j = j0 + mm;
        const float2 pj = posS[j];
        uint32_t* dst = &rel32[mm * 256];
        const int sw = mm * 2;                      // pair-granular XOR swizzle
#pragma unroll
        for (int s = 0; s < 8; ++s) {
            uint32_t word = 0;
#pragma unroll
            for (int qq = 0; qq < 4; ++qq) {
                int i = grp * 32 + s * 4 + qq;
                float2 pi = posS[i];
                float dx = pj.x - pi.x, dy = pj.y - pi.y;
                // faithful priority chain of _get_relation_type
                int r = (dy > 0.5f) ? 0
                      : (dy < -0.5f) ? 1
                      : (dx < -0.5f) ? 2
                      : (dx > 0.5f)  ? 3
                      : (fabsf(dx) < 0.3f && fabsf(dy) < 0.3f) ? 4
                      : 5;
                uint32_t oh = (i == j) ? 0u : (1u << r);
                word |= oh << (8 * qq);
            }
            dst[(grp * 8 + s) ^ sw] = word;
        }
    }
    BARRIER_LGKM();

    // ---- phase 2: masked GEMM, 8 chunks of 128 i, BARRIER-FREE streaming ----
    f32x4 acc[5];
#pragma unroll
    for (int r = 0; r < 5; ++r) acc[r] = (f32x4){0.f, 0.f, 0.f, 0.f};

    const int E = (w << 4) + m;      // e-row owned by this lane
    const int esw = m;               // == E & 15
    const int csw = m * 2;

    for (int c = 0; c < 8; ++c) {
        if (c < 7) {
            issue_chunk(c + 1, (c + 1) & 1);              // prefetch next chunk
            asm volatile("s_waitcnt vmcnt(4)" ::: "memory");  // chunk c landed
        } else {
            asm volatile("s_waitcnt vmcnt(0)" ::: "memory");
        }
        const uint16_t* bt = symTS + ((c & 1) << 14) + E * 128;
        const uint32_t* crow = &rel32[m * 256 + c * 32];
#pragma unroll
        for (int ks = 0; ks < 4; ++ks) {
            U4B bfr;
            bfr.u = *(const uint4*)(bt + ((((ks << 2) + q) ^ esw) << 3));
            uint2 cw = *(const uint2*)&crow[(((ks << 3) + (q << 1)) ^ csw)];
            // byte -> halfword expansion (shared across r)
            uint32_t hx01 = __builtin_amdgcn_perm(cw.x, cw.x, 0x01010000u) & 0x00FF00FFu;
            uint32_t hx23 = __builtin_amdgcn_perm(cw.x, cw.x, 0x03030202u) & 0x00FF00FFu;
            uint32_t hy01 = __builtin_amdgcn_perm(cw.y, cw.y, 0x01010000u) & 0x00FF00FFu;
            uint32_t hy23 = __builtin_amdgcn_perm(cw.y, cw.y, 0x03030202u) & 0x00FF00FFu;
#pragma unroll
            for (int r = 0; r < 5; ++r) {
                const uint32_t rm = 0x00010001u << r;
                U4B a;
#ifdef OH_MUL24
                const uint32_t mc = 0x3F80u >> r;   // 2^r * mc == 0x3F80 (bf16 1.0)
                a.u.x = (uint32_t)__builtin_amdgcn_mul_u24((int)(hx01 & rm), (int)mc);
                a.u.y = (uint32_t)__builtin_amdgcn_mul_u24((int)(hx23 & rm), (int)mc);
                a.u.z = (uint32_t)__builtin_amdgcn_mul_u24((int)(hy01 & rm), (int)mc);
                a.u.w = (uint32_t)__builtin_amdgcn_mul_u24((int)(hy23 & rm), (int)mc);
#else
                uint32_t g2;
                g2 = hx01 & rm; a.u.x = (g2 << (14 - r)) - (g2 << (7 - r));
                g2 = hx23 & rm; a.u.y = (g2 << (14 - r)) - (g2 << (7 - r));
                g2 = hy01 & rm; a.u.z = (g2 << (14 - r)) - (g2 << (7 - r));
                g2 = hy23 & rm; a.u.w = (g2 << (14 - r)) - (g2 << (7 - r));
#endif
                acc[r] = __builtin_amdgcn_mfma_f32_16x16x32_bf16(a.b, bfr.b, acc[r], 0, 0, 0);
            }
        }
        // no barrier: wave only touches its own buffer regions.
    }
    BARRIER_LGKM();   // all waves done reading symTS before SA overwrites it

    // ---- phase 3: S (bf16, via LDS) @ WtB, 4-way K-split over wave pairs ----
#pragma unroll
    for (int r = 0; r < 5; ++r)
#pragma unroll
        for (int reg = 0; reg < 4; ++reg)
            SA[(q * 4 + reg) * SP + r * 128 + E] = f2bf(acc[r][reg]);
    {
        // r=5 by complement: S5 = T_b - sym[j] - sum_{r<5} S_r
        float ts = T4[((b << 2) + 0) * 128 + E] + T4[((b << 2) + 1) * 128 + E]
                 + T4[((b << 2) + 2) * 128 + E] + T4[((b << 2) + 3) * 128 + E];
#pragma unroll
        for (int reg = 0; reg < 4; ++reg) {
            float symj = sym[((size_t)((b << 10) + j0 + (q << 2) + reg) << 7) + E];
            float s5 = ts - symj
                     - acc[0][reg] - acc[1][reg] - acc[2][reg] - acc[3][reg] - acc[4][reg];
            SA[(q * 4 + reg) * SP + 5 * 128 + E] = f2bf(s5);
        }
    }
    BARRIER_LGKM();

    {
        const int g = w >> 1, h = w & 1;
        f32x4 c2[4];
#pragma unroll
        for (int nf = 0; nf < 4; ++nf) c2[nf] = (f32x4){0.f, 0.f, 0.f, 0.f};
#pragma unroll
        for (int kf = 0; kf < 6; ++kf) {
            U4B af;
            af.u = *(const uint4*)&SA[m * SP + g * 192 + kf * 32 + q * 8];
            const int kb = g * 6 + kf;
#pragma unroll
            for (int nf = 0; nf < 4; ++nf) {
                U4B bw;
                bw.u = *(const uint4*)&WtB[((size_t)(kb * 128 + h * 64 + nf * 16 + m)) * 32 + q * 8];
                c2[nf] = __builtin_amdgcn_mfma_f32_16x16x32_bf16(af.b, bw.b, c2[nf], 0, 0, 0);
            }
        }
#pragma unroll
        for (int nf = 0; nf < 4; ++nf)
#pragma unroll
            for (int reg = 0; reg < 4; ++reg)
                partial[g * 2112 + (q * 4 + reg) * 132 + h * 64 + nf * 16 + m] = c2[nf][reg];
    }
    BARRIER_LGKM();

    // ---- epilogue: reduce K-split partials + sym + cnt_r*bias ----
    // counts for r<5 recomputed from rel32 (intact; swizzle is row-internal);
    // cnt5 = 1023 - sum (relations partition i != j).
    {
        const int j = tid >> 5, t = tid & 31, e0 = t << 2;
        const uint32_t* row = &rel32[j * 256 + t * 8];
        uint32_t s0 = 0, s1 = 0, s2 = 0, s3 = 0, s4 = 0;
#pragma unroll
        for (int k = 0; k < 8; ++k) {
            uint32_t wd = row[k];
            s0 += wd & 0x01010101u;        s1 += (wd >> 1) & 0x01010101u;
            s2 += (wd >> 2) & 0x01010101u; s3 += (wd >> 3) & 0x01010101u;
            s4 += (wd >> 4) & 0x01010101u;
        }
        int cnt[6];
        cnt[0] = (int)((s0 * 0x01010101u) >> 24);
        cnt[1] = (int)((s1 * 0x01010101u) >> 24);
        cnt[2] = (int)((s2 * 0x01010101u) >> 24);
        cnt[3] = (int)((s3 * 0x01010101u) >> 24);
        cnt[4] = (int)((s4 * 0x01010101u) >> 24);
#pragma unroll
        for (int off = 1; off < 32; off <<= 1)
#pragma unroll
            for (int r = 0; r < 5; ++r)
                cnt[r] += __shfl_xor(cnt[r], off, 64);   // half-wave reduce
        cnt[5] = 1023 - cnt[0] - cnt[1] - cnt[2] - cnt[3] - cnt[4];

        float4 a4 = {0.f, 0.f, 0.f, 0.f};
#pragma unroll
        for (int g4 = 0; g4 < 4; ++g4) {
            float4 u = *(const float4*)&partial[g4 * 2112 + j * 132 + e0];
            a4.x += u.x; a4.y += u.y; a4.z += u.z; a4.w += u.w;
        }
#pragma unroll
        for (int r = 0; r < 6; ++r) {
            float cf = (float)cnt[r];
            float4 bb = *(const float4*)&bias[r * 128 + e0];
            a4.x += cf * bb.x; a4.y += cf * bb.y; a4.z += cf * bb.z; a4.w += cf * bb.w;
        }
        size_t o = ((size_t)(b * 1024 + j0 + j) << 7) + e0;
        float4 sv = *(const float4*)&sym[o];
        float4 ov = { sv.x + a4.x, sv.y + a4.y, sv.z + a4.z, sv.w + a4.w };
        *(float4*)&out[o] = ov;
    }
}

extern "C" void kernel_launch(void* const* d_in, const int* in_sizes, int n_in,
                              void* d_out, int out_size, void* d_ws, size_t ws_size,
                              hipStream_t stream) {
    const float* symbols   = (const float*)d_in[0];  // [8,1024,128]
    const float* positions = (const float*)d_in[1];  // [8,1024,2]
    const float* W         = (const float*)d_in[2];  // [6,128,128]
    const float* bias      = (const float*)d_in[3];  // [6,128]
    float* out             = (float*)d_out;          // [8,1024,128]

    char* ws = (char*)d_ws;
    uint16_t* symT = (uint16_t*)ws;                  // 8*128*1024 bf16 = 2,097,152 B
    uint16_t* WtB  = (uint16_t*)(ws + 2097152);      // 24*128*32 bf16 =   196,608 B
    float*    T4   = (float*)(ws + 2097152 + 196608);// 8*4*128 f32    =    16,384 B

    prep_kernel<<<384, 256, 0, stream>>>(symbols, W, symT, WtB, T4);
    fused_kernel<<<512, 512, 0, stream>>>(symbols, positions, symT, WtB, bias, T4, out);
}

// Round 2
// 93.880 us; speedup vs baseline: 1.0013x; 1.0013x over previous
//
#include <hip/hip_runtime.h>
#include <stdint.h>

// out[b,j,:] = sym[b,j,:] + sum_{i!=j} (sym[b,i,:] @ W[rel(i,j)].T + bias[rel(i,j)])
// B=8, N=1024, D=128, 6 relations.
//
// Linearity rewrite:  agg[j] = sum_r (sum_{i!=j, rel=r} sym[i]) @ W[r].T + cnt_r(j)*bias[r]
//  1. prep: symT bf16 [8][128 e][1024 i]; WtB bf16 blocked; T4[b][quarter][e] colsums
//  2. fused (512 thr = 8 e-waves): classify -> shared-A masked MFMA (S_r, r<5)
//     -> S5 by complement -> S @ Wt (K=768) -> + sym + cnt*bias.
//
// R12 (this round): R11's barrier-free loop gave only ~10% (fused ~40us, now
// hidden under the harness's 41us 256MiB poison fills in top-5). Root cause
// reassessment: the mask A-fragments are IDENTICAL across all 8 waves (waves
// split e; A depends only on j,i,r) -> ~1536 VALU/thread of 8x-redundant
// expansion dominated issue. Fix: expand A ONCE per block into shared LDS
// (double-buffered, 64-i chunks), all waves ds_read_b128 the frags:
//   per-wave per 64-i: 192->~15 VALU, +10 A-reads; 1 lgkm barrier/chunk.
// LDS 75008 B (B 2x16K @0, A 2x10K @32768, SA 24832 @0 / partial @24832
// overlay, rel32 16K @58624) -> 2 blocks/CU. DMA stays per-wave with
// vmcnt(2); all new layouts XOR-swizzled (8 lanes per bank-residue).

typedef __attribute__((ext_vector_type(8))) short bf16x8;
typedef __attribute__((ext_vector_type(4))) float f32x4;
union U4B { uint4 u; bf16x8 b; };

#if defined(__has_builtin)
#  if __has_builtin(__builtin_amdgcn_global_load_lds)
#    define HAVE_GLL 1
#  endif
#  if __has_builtin(__builtin_amdgcn_mul_u24)
#    define OH_MUL24 1
#  endif
#endif

__device__ __forceinline__ uint16_t f2bf(float f) {
    union { float f; uint32_t u; } v; v.f = f;
    uint32_t u = v.u;
    uint32_t r = (u + 0x7FFFu + ((u >> 16) & 1u)) >> 16;  // RNE
    return (uint16_t)r;
}

// raw barrier: orders LDS only; never drains vmcnt (DMA stays in flight).
#define BARRIER_LGKM() do {                                   \
    asm volatile("s_waitcnt lgkmcnt(0)" ::: "memory");        \
    __builtin_amdgcn_s_barrier();                             \
    asm volatile("" ::: "memory");                            \
} while (0)

// ---------------------------------------------------------------------------
// prep: blocks 0..255: transpose X[b][i][e] fp32 -> symT[b][e][i] bf16 (64x64)
//       blocks 256..351: W[r][ep][e] fp32 -> WtB blocked bf16
//       blocks 352..383: T4[b][qq][e] = sum_{i in qq*256..+256} X[b][i][e]
// ---------------------------------------------------------------------------
__global__ __launch_bounds__(256)
void prep_kernel(const float* __restrict__ X, const float* __restrict__ W,
                 uint16_t* __restrict__ symT, uint16_t* __restrict__ WtB,
                 float* __restrict__ T4) {
    const int blk = blockIdx.x, tid = threadIdx.x;
    if (blk < 256) {
        __shared__ float T[64 * 65];
        const int b = blk & 7, z = blk >> 3, it = z & 15, et = z >> 4;
        const int i0 = it * 64, e0 = et * 64;
        const float4* Xf = (const float4*)X;
#pragma unroll
        for (int s = 0; s < 4; ++s) {
            int il = s * 16 + (tid >> 4), e4 = tid & 15;
            float4 v = Xf[((size_t)b << 15) + (size_t)((i0 + il) << 5) + (e0 >> 2) + e4];
            T[il * 65 + e4 * 4 + 0] = v.x;
            T[il * 65 + e4 * 4 + 1] = v.y;
            T[il * 65 + e4 * 4 + 2] = v.z;
            T[il * 65 + e4 * 4 + 3] = v.w;
        }
        __syncthreads();
#pragma unroll
        for (int s = 0; s < 4; ++s) {
            int el = s * 16 + (tid >> 4), il4 = tid & 15;
            uint16_t h0 = f2bf(T[(il4 * 4 + 0) * 65 + el]);
            uint16_t h1 = f2bf(T[(il4 * 4 + 1) * 65 + el]);
            uint16_t h2 = f2bf(T[(il4 * 4 + 2) * 65 + el]);
            uint16_t h3 = f2bf(T[(il4 * 4 + 3) * 65 + el]);
            uint2 pk = { (uint32_t)h0 | ((uint32_t)h1 << 16),
                         (uint32_t)h2 | ((uint32_t)h3 << 16) };
            *(uint2*)&symT[((size_t)b << 17) + ((size_t)(e0 + el) << 10) + i0 + il4 * 4] = pk;
        }
    } else if (blk < 352) {
        int g = (blk - 256) * 256 + tid;          // 0..24575 float4s of W
        float4 v = ((const float4*)W)[g];
        int r = g >> 12, rem = g & 4095, ep = rem >> 5, e4 = rem & 31;
        int kb = r * 4 + (e4 >> 3);               // k = r*128 + e4*4+t
        int kc = (e4 & 7) * 4;
        uint16_t h0 = f2bf(v.x), h1 = f2bf(v.y), h2 = f2bf(v.z), h3 = f2bf(v.w);
        uint2 pk = { (uint32_t)h0 | ((uint32_t)h1 << 16),
                     (uint32_t)h2 | ((uint32_t)h3 << 16) };
        *(uint2*)&WtB[((size_t)(kb * 128 + ep)) * 32 + kc] = pk;
    } else {
        // T4: per-b quarter column sums (fp32), 32 blocks = (b, quarter)
        const int z = blk - 352, bb = z >> 2, qq = z & 3;
        const int e = tid & 127, half = tid >> 7;
        const float* base = X + (((size_t)(bb << 10) + (qq << 8) + (half << 7)) << 7) + e;
        float s = 0.f;
#pragma unroll 8
        for (int itr = 0; itr < 128; ++itr) s += base[(size_t)itr << 7];
        __shared__ float red[256];
        red[tid] = s;
        __syncthreads();
        if (tid < 128) T4[(z << 7) + tid] = red[tid] + red[tid + 128];
    }
}

// ---------------------------------------------------------------------------
// fused kernel: grid 512 = 8b x 64jt (16 j per block), 512 thr = 8 waves.
// LDS map (75008 B -> 2 blocks/CU):
//   @0      B double buffer: 2 x 16384 (64-i chunk: wave w owns [w*2048,+2048),
//           16 e-rows x 128 B, 16B segs XOR-swizzled seg' = seg ^ (e&7)).
//           After phase 2: SA 24832 @0, partial 33792 @24832 (ends 58624).
//   @32768  A-frag double buffer: 2 x 10240 (5 r x 16 j rows x 128 B,
//           seg' = seg ^ (j&7)); head doubles as posS (8 KB) during classify.
//   @58624  rel32: 16 j x 256 dwords, dword-pair swizzle (d ^ 2j), 16384 B.
// ---------------------------------------------------------------------------
#define SP 776

__global__ __launch_bounds__(512, 4)
void fused_kernel(const float* __restrict__ sym, const float* __restrict__ pos,
                  const uint16_t* __restrict__ symT, const uint16_t* __restrict__ WtB,
                  const float* __restrict__ bias, const float* __restrict__ T4,
                  float* __restrict__ out) {
    __shared__ __align__(16) char smem[75008];
    float2*   posS    = (float2*)(smem + 32768);
    uint16_t* SA      = (uint16_t*)smem;
    float*    partial = (float*)(smem + 24832);
    uint32_t* rel32   = (uint32_t*)(smem + 58624);

    const int blk = blockIdx.x;
    const int b = blk & 7, jt = blk >> 3, j0 = jt * 16;
    const int tid = threadIdx.x;
    const int w = tid >> 6, lane = tid & 63, m = lane & 15, q = lane >> 4;

    const uint16_t* symTb = symT + ((size_t)b << 17);

    // --- B staging: wave w DMAs its own 16 e-rows, 64-i chunks, 2 issues ---
    // issue s, lane l: e = w*16 + s*8 + (l>>3); dest seg t = l&7 holds global
    // seg t ^ (e&7)  (consumer reads seg' = seg ^ (e&7)).
    int goff[2];
#pragma unroll
    for (int s = 0; s < 2; ++s) {
        int e = (w << 4) + (s << 3) + (lane >> 3);
        int t = lane & 7;
        goff[s] = (e << 10) + ((t ^ (e & 7)) << 3);   // halfword units; + c*64
    }

    auto issue_chunk = [&](int cidx, int bufsel) {
#ifdef HAVE_GLL
#pragma unroll
        for (int s = 0; s < 2; ++s) {
            const uint16_t* gp = symTb + goff[s] + cidx * 64;
            char* lp = smem + bufsel * 16384 + (w << 11) + (s << 10);  // wave-uniform
            typedef const __attribute__((address_space(1))) uint32_t gu32;
            typedef __attribute__((address_space(3))) uint32_t lu32;
            __builtin_amdgcn_global_load_lds((gu32*)gp, (lu32*)lp, 16, 0, 0);
        }
#else
#pragma unroll
        for (int s = 0; s < 2; ++s) {
            uint4 v = *(const uint4*)(symTb + goff[s] + cidx * 64);
            *(uint4*)(smem + bufsel * 16384 + (w << 11) + (s << 10) + lane * 16) = v;
        }
#endif
    };

    // --- shared A-frag expansion: thread (jx, u16, rsub) covers chunk's
    //     (j=jx, i4 = u16 -> 4 i) for r-subset {0,1,2} or {3,4}. ---
    const int jx = tid & 15, u16 = (tid >> 4) & 15, rsub = tid >> 8;
    const int aseg = (u16 >> 1) ^ (jx & 7), ahb = (u16 & 1) * 8;

    auto expandA = [&](int cidx, int bufsel) {
        uint32_t cw4 = rel32[jx * 256 + (((cidx << 4) + u16) ^ (jx << 1))];
        uint32_t h01 = __builtin_amdgcn_perm(cw4, cw4, 0x01010000u) & 0x00FF00FFu;
        uint32_t h23 = __builtin_amdgcn_perm(cw4, cw4, 0x03030202u) & 0x00FF00FFu;
        char* ab = smem + 32768 + bufsel * 10240;
        if (rsub == 0) {
#pragma unroll
            for (int r = 0; r < 3; ++r) {
                const uint32_t rm = 0x00010001u << r;
                uint2 d;
#ifdef OH_MUL24
                const uint32_t mc = 0x3F80u >> r;
                d.x = (uint32_t)__builtin_amdgcn_mul_u24((int)(h01 & rm), (int)mc);
                d.y = (uint32_t)__builtin_amdgcn_mul_u24((int)(h23 & rm), (int)mc);
#else
                uint32_t g2;
                g2 = h01 & rm; d.x = (g2 << (14 - r)) - (g2 << (7 - r));
                g2 = h23 & rm; d.y = (g2 << (14 - r)) - (g2 << (7 - r));
#endif
                *(uint2*)(ab + (((r * 16 + jx) * 8 + aseg) << 4) + ahb) = d;
            }
        } else {
#pragma unroll
            for (int r = 3; r < 5; ++r) {
                const uint32_t rm = 0x00010001u << r;
                uint2 d;
#ifdef OH_MUL24
                const uint32_t mc = 0x3F80u >> r;
                d.x = (uint32_t)__builtin_amdgcn_mul_u24((int)(h01 & rm), (int)mc);
                d.y = (uint32_t)__builtin_amdgcn_mul_u24((int)(h23 & rm), (int)mc);
#else
                uint32_t g2;
                g2 = h01 & rm; d.x = (g2 << (14 - r)) - (g2 << (7 - r));
                g2 = h23 & rm; d.y = (g2 << (14 - r)) - (g2 << (7 - r));
#endif
                *(uint2*)(ab + (((r * 16 + jx) * 8 + aseg) << 4) + ahb) = d;
            }
        }
    };

    // ---- phase 0: chunk-0 DMA in flight under classify; stage positions ----
    issue_chunk(0, 0);
    const float2* pos2 = (const float2*)pos + ((size_t)b << 10);
    float2 p0 = pos2[tid], p1 = pos2[tid + 512];
    posS[tid] = p0;
    posS[tid + 512] = p1;
    BARRIER_LGKM();

    // ---- phase 1: classify 16 j x 1024 i -> one-hot bytes (0 on diagonal) ----
    {
        const int mm = tid & 15, grp = tid >> 4;    // grp 0..31: 32 i's each
        const int j = j0 + mm;
        const float2 pj = posS[j];
        uint32_t* dst = &rel32[mm * 256];
        const int sw = mm * 2;                      // pair-granular XOR swizzle
#pragma unroll
        for (int s = 0; s < 8; ++s) {
            uint32_t word = 0;
#pragma unroll
            for (int qq = 0; qq < 4; ++qq) {
                int i = grp * 32 + s * 4 + qq;
                float2 pi = posS[i];
                float dx = pj.x - pi.x, dy = pj.y - pi.y;
                // faithful priority chain of _get_relation_type
                int r = (dy > 0.5f) ? 0
                      : (dy < -0.5f) ? 1
                      : (dx < -0.5f) ? 2
                      : (dx > 0.5f)  ? 3
                      : (fabsf(dx) < 0.3f && fabsf(dy) < 0.3f) ? 4
                      : 5;
                uint32_t oh = (i == j) ? 0u : (1u << r);
                word |= oh << (8 * qq);
            }
            dst[(grp * 8 + s) ^ sw] = word;
        }
    }
    BARRIER_LGKM();            // rel32 ready; posS dead

    // prologue: expand chunk-0 A-frags (overwrites posS region)
    expandA(0, 0);
    BARRIER_LGKM();

    // ---- phase 2: shared-A masked GEMM, 16 chunks of 64 i ----
    f32x4 acc[5];
#pragma unroll
    for (int r = 0; r < 5; ++r) acc[r] = (f32x4){0.f, 0.f, 0.f, 0.f};

    const int E = (w << 4) + m;          // e-row owned by this lane (E&7 == m&7)
    const int bseg0 = q ^ (m & 7);       // ks=0 seg; ks=1 seg = (4+q)^(m&7)
    const int bseg1 = (4 + q) ^ (m & 7);

    for (int c = 0; c < 16; ++c) {
        const int cb = c & 1;
        if (c < 15) {
            issue_chunk(c + 1, cb ^ 1);                   // prefetch next B
            expandA(c + 1, cb ^ 1);                       // expand next A
            asm volatile("s_waitcnt vmcnt(2)" ::: "memory");  // chunk c's B landed
        } else {
            asm volatile("s_waitcnt vmcnt(0)" ::: "memory");
        }
        const char* bb = smem + cb * 16384 + (w << 11) + (m << 7);
        const char* ab = smem + 32768 + cb * 10240;
#pragma unroll
        for (int ks = 0; ks < 2; ++ks) {
            U4B bfr;
            bfr.u = *(const uint4*)(bb + ((ks ? bseg1 : bseg0) << 4));
#pragma unroll
            for (int r = 0; r < 5; ++r) {
                U4B afr;
                afr.u = *(const uint4*)(ab + ((((r * 16 + m) * 8) +
                                               (ks ? bseg1 : bseg0)) << 4));
                acc[r] = __builtin_amdgcn_mfma_f32_16x16x32_bf16(afr.b, bfr.b, acc[r], 0, 0, 0);
            }
        }
        BARRIER_LGKM();   // publish A[c+1]; release B[c] region for c+2 DMA
    }

    // ---- phase 3: S (bf16, via LDS) @ WtB, 4-way K-split over wave pairs ----
#pragma unroll
    for (int r = 0; r < 5; ++r)
#pragma unroll
        for (int reg = 0; reg < 4; ++reg)
            SA[(q * 4 + reg) * SP + r * 128 + E] = f2bf(acc[r][reg]);
    {
        // r=5 by complement: S5 = T_b - sym[j] - sum_{r<5} S_r
        float ts = T4[((b << 2) + 0) * 128 + E] + T4[((b << 2) + 1) * 128 + E]
                 + T4[((b << 2) + 2) * 128 + E] + T4[((b << 2) + 3) * 128 + E];
#pragma unroll
        for (int reg = 0; reg < 4; ++reg) {
            float symj = sym[((size_t)((b << 10) + j0 + (q << 2) + reg) << 7) + E];
            float s5 = ts - symj
                     - acc[0][reg] - acc[1][reg] - acc[2][reg] - acc[3][reg] - acc[4][reg];
            SA[(q * 4 + reg) * SP + 5 * 128 + E] = f2bf(s5);
        }
    }
    BARRIER_LGKM();

    {
        const int g = w >> 1, h = w & 1;
        f32x4 c2[4];
#pragma unroll
        for (int nf = 0; nf < 4; ++nf) c2[nf] = (f32x4){0.f, 0.f, 0.f, 0.f};
#pragma unroll
        for (int kf = 0; kf < 6; ++kf) {
            U4B af;
            af.u = *(const uint4*)&SA[m * SP + g * 192 + kf * 32 + q * 8];
            const int kb = g * 6 + kf;
#pragma unroll
            for (int nf = 0; nf < 4; ++nf) {
                U4B bw;
                bw.u = *(const uint4*)&WtB[((size_t)(kb * 128 + h * 64 + nf * 16 + m)) * 32 + q * 8];
                c2[nf] = __builtin_amdgcn_mfma_f32_16x16x32_bf16(af.b, bw.b, c2[nf], 0, 0, 0);
            }
        }
#pragma unroll
        for (int nf = 0; nf < 4; ++nf)
#pragma unroll
            for (int reg = 0; reg < 4; ++reg)
                partial[g * 2112 + (q * 4 + reg) * 132 + h * 64 + nf * 16 + m] = c2[nf][reg];
    }
    BARRIER_LGKM();

    // ---- epilogue: reduce K-split partials + sym + cnt_r*bias ----
    // counts for r<5 recomputed from rel32 (intact; swizzle is row-internal);
    // cnt5 = 1023 - sum (relations partition i != j).
    {
        const int j = tid >> 5, t = tid & 31, e0 = t << 2;
        const uint32_t* row = &rel32[j * 256 + t * 8];
        uint32_t s0 = 0, s1 = 0, s2 = 0, s3 = 0, s4 = 0;
#pragma unroll
        for (int k = 0; k < 8; ++k) {
            uint32_t wd = row[k];
            s0 += wd & 0x01010101u;        s1 += (wd >> 1) & 0x01010101u;
            s2 += (wd >> 2) & 0x01010101u; s3 += (wd >> 3) & 0x01010101u;
            s4 += (wd >> 4) & 0x01010101u;
        }
        int cnt[6];
        cnt[0] = (int)((s0 * 0x01010101u) >> 24);
        cnt[1] = (int)((s1 * 0x01010101u) >> 24);
        cnt[2] = (int)((s2 * 0x01010101u) >> 24);
        cnt[3] = (int)((s3 * 0x01010101u) >> 24);
        cnt[4] = (int)((s4 * 0x01010101u) >> 24);
#pragma unroll
        for (int off = 1; off < 32; off <<= 1)
#pragma unroll
            for (int r = 0; r < 5; ++r)
                cnt[r] += __shfl_xor(cnt[r], off, 64);   // half-wave reduce
        cnt[5] = 1023 - cnt[0] - cnt[1] - cnt[2] - cnt[3] - cnt[4];

        float4 a4 = {0.f, 0.f, 0.f, 0.f};
#pragma unroll
        for (int g4 = 0; g4 < 4; ++g4) {
            float4 u = *(const float4*)&partial[g4 * 2112 + j * 132 + e0];
            a4.x += u.x; a4.y += u.y; a4.z += u.z; a4.w += u.w;
        }
#pragma unroll
        for (int r = 0; r < 6; ++r) {
            float cf = (float)cnt[r];
            float4 bb = *(const float4*)&bias[r * 128 + e0];
            a4.x += cf * bb.x; a4.y += cf * bb.y; a4.z += cf * bb.z; a4.w += cf * bb.w;
        }
        size_t o = ((size_t)(b * 1024 + j0 + j) << 7) + e0;
        float4 sv = *(const float4*)&sym[o];
        float4 ov = { sv.x + a4.x, sv.y + a4.y, sv.z + a4.z, sv.w + a4.w };
        *(float4*)&out[o] = ov;
    }
}

extern "C" void kernel_launch(void* const* d_in, const int* in_sizes, int n_in,
                              void* d_out, int out_size, void* d_ws, size_t ws_size,
                              hipStream_t stream) {
    const float* symbols   = (const float*)d_in[0];  // [8,1024,128]
    const float* positions = (const float*)d_in[1];  // [8,1024,2]
    const float* W         = (const float*)d_in[2];  // [6,128,128]
    const float* bias      = (const float*)d_in[3];  // [6,128]
    float* out             = (float*)d_out;          // [8,1024,128]

    char* ws = (char*)d_ws;
    uint16_t* symT = (uint16_t*)ws;                  // 8*128*1024 bf16 = 2,097,152 B
    uint16_t* WtB  = (uint16_t*)(ws + 2097152);      // 24*128*32 bf16 =   196,608 B
    float*    T4   = (float*)(ws + 2097152 + 196608);// 8*4*128 f32    =    16,384 B

    prep_kernel<<<384, 256, 0, stream>>>(symbols, W, symT, WtB, T4);
    fused_kernel<<<512, 512, 0, stream>>>(symbols, positions, symT, WtB, bias, T4, out);
}